// Round 1
// 131.860 us; speedup vs baseline: 1.0339x; 1.0339x over previous
//
#include <hip/hip_runtime.h>
#include <stdint.h>
#include <stddef.h>

// ---------------- types ----------------
typedef __attribute__((ext_vector_type(8))) short bf16x8;          // MFMA A/B frag (8 bf16)
typedef __attribute__((ext_vector_type(4))) short bf16x4;          // 8B half-frag
typedef __attribute__((ext_vector_type(4))) float f32x4;           // MFMA C/D frag

typedef const __attribute__((address_space(1))) void* gptr1_t;
typedef __attribute__((address_space(3))) void* lptr3_t;

#define GLOAD_LDS16(gp, lp) \
  __builtin_amdgcn_global_load_lds((gptr1_t)(gp), (lptr3_t)(lp), 16, 0, 0)

__device__ __forceinline__ uint16_t f2bf(float f) {
  uint32_t u = __builtin_bit_cast(uint32_t, f);
  u += 0x7fffu + ((u >> 16) & 1u);   // RNE
  return (uint16_t)(u >> 16);
}

// ---------------- problem constants ----------------
#define MB   16384      // batch
#define NP   256        // W*H positions
#define KDIM 1024       // NP*EMB
#define NDIM 1024       // OUT
#define NCLS 1024       // embedding classes

#define BM  128
#define BN  128
#define BKH 32
#define BK  64          // 16 positions per K-step
#define NK  (KDIM / BK) // 16

// ---------------- kernel 1: Bt[n][k] = bf16(W_dense[k][n]) (transpose + cast) ----------------
__global__ void build_bt_kernel(const float* __restrict__ Wd,
                                uint16_t* __restrict__ Bt) {
  __shared__ uint16_t tile[32][33];               // +1 pad: no bank conflicts
  const int k0 = blockIdx.y * 32;
  const int n0 = blockIdx.x * 32;
  const int tx = threadIdx.x;                     // 0..31
  const int ty = threadIdx.y;                     // 0..7
  #pragma unroll
  for (int r = 0; r < 32; r += 8)
    tile[ty + r][tx] = f2bf(Wd[(size_t)(k0 + ty + r) * NDIM + n0 + tx]);
  __syncthreads();
  #pragma unroll
  for (int r = 0; r < 32; r += 8)
    Bt[(size_t)(n0 + ty + r) * KDIM + k0 + tx] = tile[tx][ty + r];
}

// ---------------- kernel 2: fused embed-gather + bf16 GEMM ----------------
// C[b][n] = sum_k emb(x)[b][k] * Bt[n][k] + bias[n]
// A is never materialized: the 8-KB bias-folded bf16 embed table lives in LDS,
// and each lane builds its A-fragment (8 k's = 2 positions = 2 table rows)
// with two ds_read_b64 gathers. x is staged per K-step in LDS (8 KB,
// pair-major [p2][row] so the fragment-read is only 4-way conflicted).
__global__ __launch_bounds__(256) void fused_gemm_kernel(
    const int* __restrict__ x,
    const float* __restrict__ We,
    const float* __restrict__ be,
    const uint16_t* __restrict__ Bt,
    const float* __restrict__ bias,
    float* __restrict__ C) {
  __shared__ uint16_t web[NCLS * 4];     // 8 KB: bf16(We[c][e] + be[e]), class-major
  __shared__ int      xs[8 * 256];       // 8 KB: pair slot p2 (0..7) x row (0..127) -> 2 ints
  __shared__ uint16_t Bs[2][BN * BKH];   // 16 KB: two 128x32 half-tiles

  const int tid  = threadIdx.x;
  const int bm   = blockIdx.x;
  const int bn   = blockIdx.y;
  const int wave = tid >> 6;
  const int lane = tid & 63;
  const int wr   = wave >> 1;            // 2x2 wave grid, 64x64 per wave
  const int wc   = wave & 1;
  const int lm   = lane & 15;
  const int q    = lane >> 4;

  const int row0 = bm * BM;
  const int col0 = bn * BN;

  // ---- embed table -> LDS (bias folded, bf16) ----
  {
    const float4 bb = *(const float4*)be;
    for (int c = tid; c < NCLS; c += 256) {
      const float4 w = *(const float4*)(We + (size_t)c * 4);
      bf16x4 t;
      t[0] = (short)f2bf(w.x + bb.x);
      t[1] = (short)f2bf(w.y + bb.y);
      t[2] = (short)f2bf(w.z + bb.z);
      t[3] = (short)f2bf(w.w + bb.w);
      *(bf16x4*)(web + (size_t)c * 4) = t;
    }
  }

  // ---- staging coords ----
  const int srow  = tid >> 2;            // B: 0..63
  const int scol  = (tid & 3) * 8;       // B: 8 bf16 = 16B
  const int xrow  = tid >> 2;            // x: row within 64-row half
  const int xpos4 = (tid & 3) * 4;       // x: 4 positions (one int4)
  const int p2w   = (tid & 3) * 2;       // x: pair-slot base

  f32x4 acc[4][4];
  #pragma unroll
  for (int i = 0; i < 4; i++)
    #pragma unroll
    for (int j = 0; j < 4; j++)
      acc[i][j] = (f32x4){0.f, 0.f, 0.f, 0.f};

  const int* xrp_a = x + (size_t)(row0      + xrow) * NP;  // rows 0..63
  const int* xrp_b = x + (size_t)(row0 + 64 + xrow) * NP;  // rows 64..127

  // prologue: x int4 loads for kt=0 (16B, segment-coalesced)
  int4 xqa = *(const int4*)(xrp_a + xpos4);
  int4 xqb = *(const int4*)(xrp_b + xpos4);

  // precomputed fragment-read base (word units): pair (h*4+q, row=wr*64+i*16+lm)
  const int xrd_base = (q << 8) + ((wr * 64 + lm) << 1);

  for (int kt = 0; kt < NK; ++kt) {
    // ---- write this K-step's x pairs into LDS (pair-major) ----
    {
      const int ra2 = xrow * 2;
      const int rb2 = (64 + xrow) * 2;
      int2 v;
      v.x = xqa.x; v.y = xqa.y; *(int2*)(xs + (p2w    ) * 256 + ra2) = v;
      v.x = xqa.z; v.y = xqa.w; *(int2*)(xs + (p2w + 1) * 256 + ra2) = v;
      v.x = xqb.x; v.y = xqb.y; *(int2*)(xs + (p2w    ) * 256 + rb2) = v;
      v.x = xqb.z; v.y = xqb.w; *(int2*)(xs + (p2w + 1) * 256 + rb2) = v;
    }

    // ---- B staging: async global->LDS, two 128x32 half-tiles ----
    const int k0 = kt * BK;
    #pragma unroll
    for (int h = 0; h < 2; ++h) {
      GLOAD_LDS16(Bt + (size_t)(col0      + srow) * KDIM + k0 + h * BKH + scol, Bs[h] + tid * 8);
      GLOAD_LDS16(Bt + (size_t)(col0 + 64 + srow) * KDIM + k0 + h * BKH + scol, Bs[h] + 2048 + tid * 8);
    }

    // ---- prefetch next K-step's x (latency hides behind the barrier drain) ----
    if (kt + 1 < NK) {
      xqa = *(const int4*)(xrp_a + (kt + 1) * 16 + xpos4);
      xqb = *(const int4*)(xrp_b + (kt + 1) * 16 + xpos4);
    }

    __syncthreads();

    #pragma unroll
    for (int h = 0; h < 2; ++h) {
      bf16x8 af[4], bfr[4];
      // A-frags: read class pair from xs, gather 2x8B from the LDS table
      #pragma unroll
      for (int i = 0; i < 4; i++) {
        const int2 xp = *(const int2*)(xs + xrd_base + (h << 10) + (i << 5));
        union { bf16x8 v; struct { bf16x4 lo, hi; } s; } u;
        u.s.lo = *(const bf16x4*)(web + (((unsigned)xp.x) << 2));
        u.s.hi = *(const bf16x4*)(web + (((unsigned)xp.y) << 2));
        af[i] = u.v;
      }
      #pragma unroll
      for (int j = 0; j < 4; j++)
        bfr[j] = *(const bf16x8*)(Bs[h] + (wc * 64 + j * 16 + lm) * BKH + q * 8);

      #pragma unroll
      for (int i = 0; i < 4; i++)
        #pragma unroll
        for (int j = 0; j < 4; j++)
          acc[i][j] = __builtin_amdgcn_mfma_f32_16x16x32_bf16(af[i], bfr[j], acc[i][j], 0, 0, 0);
    }

    __syncthreads();
  }

  // ---- epilogue: D[row = q*4 + r][col = lm] per 16x16 frag (m89/m91-verified) ----
  float bvals[4];
  #pragma unroll
  for (int j = 0; j < 4; j++)
    bvals[j] = bias[col0 + wc * 64 + j * 16 + lm];

  #pragma unroll
  for (int i = 0; i < 4; i++) {
    const int rbase = row0 + wr * 64 + i * 16 + q * 4;
    #pragma unroll
    for (int j = 0; j < 4; j++) {
      const int col = col0 + wc * 64 + j * 16 + lm;
      #pragma unroll
      for (int r = 0; r < 4; r++)
        C[(size_t)(rbase + r) * NDIM + col] = acc[i][j][r] + bvals[j];
    }
  }
}

// ---------------- fallback (workspace too small): fp32 naive ----------------
__global__ void naive_kernel(const int* __restrict__ x,
                             const float* __restrict__ We,
                             const float* __restrict__ be,
                             const float* __restrict__ Wd,
                             const float* __restrict__ bd,
                             float* __restrict__ out) {
  __shared__ float emb[KDIM];
  const int b = blockIdx.x;
  const int tid = threadIdx.x;
  {
    const int cls = x[(size_t)b * NP + tid];
    const float4 e  = *(const float4*)(We + (size_t)cls * 4);
    const float4 bb = *(const float4*)be;
    emb[tid * 4 + 0] = e.x + bb.x;
    emb[tid * 4 + 1] = e.y + bb.y;
    emb[tid * 4 + 2] = e.z + bb.z;
    emb[tid * 4 + 3] = e.w + bb.w;
  }
  __syncthreads();
  float acc0 = bd[tid], acc1 = bd[tid + 256], acc2 = bd[tid + 512], acc3 = bd[tid + 768];
  for (int k = 0; k < KDIM; ++k) {
    const float a = emb[k];
    const float* w = Wd + (size_t)k * NDIM + tid;
    acc0 += a * w[0];
    acc1 += a * w[256];
    acc2 += a * w[512];
    acc3 += a * w[768];
  }
  float* o = out + (size_t)b * NDIM + tid;
  o[0] = acc0; o[256] = acc1; o[512] = acc2; o[768] = acc3;
}

// ---------------- launch ----------------
extern "C" void kernel_launch(void* const* d_in, const int* in_sizes, int n_in,
                              void* d_out, int out_size, void* d_ws, size_t ws_size,
                              hipStream_t stream) {
  const int*   x  = (const int*)d_in[0];
  const float* We = (const float*)d_in[1];
  const float* be = (const float*)d_in[2];
  const float* Wd = (const float*)d_in[3];
  const float* bd = (const float*)d_in[4];
  float* out = (float*)d_out;

  const size_t needB = (size_t)NDIM * KDIM * sizeof(uint16_t);  // 2 MB

  if (ws_size >= needB) {
    uint16_t* Btw = (uint16_t*)d_ws;
    build_bt_kernel<<<dim3(NDIM / 32, KDIM / 32), dim3(32, 8), 0, stream>>>(Wd, Btw);
    fused_gemm_kernel<<<dim3(MB / BM, NDIM / BN), 256, 0, stream>>>(x, We, be, Btw, bd, out);
  } else {
    naive_kernel<<<MB, 256, 0, stream>>>(x, We, be, Wd, bd, out);
  }
}

// Round 2
// 131.354 us; speedup vs baseline: 1.0379x; 1.0039x over previous
//
#include <hip/hip_runtime.h>
#include <stdint.h>
#include <stddef.h>

// ---------------- types ----------------
typedef __attribute__((ext_vector_type(8))) short bf16x8;          // MFMA A/B frag (8 bf16)
typedef __attribute__((ext_vector_type(4))) short bf16x4;          // 8B half-frag
typedef __attribute__((ext_vector_type(4))) float f32x4;           // MFMA C/D frag

typedef const __attribute__((address_space(1))) void* gptr1_t;
typedef __attribute__((address_space(3))) void* lptr3_t;

#define GLOAD_LDS16(gp, lp) \
  __builtin_amdgcn_global_load_lds((gptr1_t)(gp), (lptr3_t)(lp), 16, 0, 0)

__device__ __forceinline__ uint16_t f2bf(float f) {
  uint32_t u = __builtin_bit_cast(uint32_t, f);
  u += 0x7fffu + ((u >> 16) & 1u);   // RNE
  return (uint16_t)(u >> 16);
}

// ---------------- problem constants ----------------
#define MB   16384      // batch
#define NP   256        // W*H positions
#define KDIM 1024       // NP*EMB
#define NDIM 1024       // OUT
#define NCLS 1024       // embedding classes

#define BM  128
#define BN  128
#define BKH 32
#define BK  64          // 16 positions per K-step
#define NK  (KDIM / BK) // 16

// ---------------- kernel 1: Bt[n][k] = bf16(W_dense[k][n]) (transpose + cast) ----------------
__global__ void build_bt_kernel(const float* __restrict__ Wd,
                                uint16_t* __restrict__ Bt) {
  __shared__ uint16_t tile[32][33];               // +1 pad: no bank conflicts
  const int k0 = blockIdx.y * 32;
  const int n0 = blockIdx.x * 32;
  const int tx = threadIdx.x;                     // 0..31
  const int ty = threadIdx.y;                     // 0..7
  #pragma unroll
  for (int r = 0; r < 32; r += 8)
    tile[ty + r][tx] = f2bf(Wd[(size_t)(k0 + ty + r) * NDIM + n0 + tx]);
  __syncthreads();
  #pragma unroll
  for (int r = 0; r < 32; r += 8)
    Bt[(size_t)(n0 + ty + r) * KDIM + k0 + tx] = tile[tx][ty + r];
}

// ---------------- kernel 2: fused embed-gather + bf16 GEMM ----------------
// C[b][n] = sum_k emb(x)[b][k] * Bt[n][k] + bias[n]
// A never touches HBM. The 8-KB bias-folded bf16 table lives in LDS; each
// K-step the block MATERIALIZES the 128x64 A-tile into LDS (each thread: 8
// register-held class indices -> 8x8B table gathers -> 4x16B ds_writes),
// done ONCE per block (round-1 version duplicated every gather 2x across
// the wc waves and paid xs-staging traffic on top). Fragment reads then use
// the round-0-verified ds_read_b128 pattern for both A and B.
__global__ __launch_bounds__(256) void fused_gemm_kernel(
    const int* __restrict__ x,
    const float* __restrict__ We,
    const float* __restrict__ be,
    const uint16_t* __restrict__ Bt,
    const float* __restrict__ bias,
    float* __restrict__ C) {
  __shared__ __align__(16) uint16_t web[NCLS * 4];     // 8 KB: bf16(We[c][e]+be[e])
  __shared__ __align__(16) uint16_t As[2][BM * BKH];   // 16 KB: two 128x32 half-tiles
  __shared__ __align__(16) uint16_t Bs[2][BN * BKH];   // 16 KB

  const int tid  = threadIdx.x;
  const int bm   = blockIdx.x;
  const int bn   = blockIdx.y;
  const int wave = tid >> 6;
  const int lane = tid & 63;
  const int wr   = wave >> 1;            // 2x2 wave grid, 64x64 per wave
  const int wc   = wave & 1;
  const int lm   = lane & 15;
  const int q    = lane >> 4;

  const int row0 = bm * BM;
  const int col0 = bn * BN;

  // ---- embed table -> LDS (bias folded, bf16) ----
  {
    const float4 bb = *(const float4*)be;
    #pragma unroll
    for (int c0 = 0; c0 < NCLS; c0 += 256) {
      const int c = c0 + tid;
      const float4 w = *(const float4*)(We + (size_t)c * 4);
      bf16x4 t;
      t[0] = (short)f2bf(w.x + bb.x);
      t[1] = (short)f2bf(w.y + bb.y);
      t[2] = (short)f2bf(w.z + bb.z);
      t[3] = (short)f2bf(w.w + bb.w);
      *(bf16x4*)(web + (size_t)c * 4) = t;
    }
  }

  // ---- staging coords ----
  const int srow = tid >> 2;             // B: 0..63
  const int scol = (tid & 3) * 8;        // B: 8 bf16 = 16B
  const int arow = tid >> 2;             // A: row within 64-row half
  const int apos = (tid & 3) * 4;        // A: position base in K-step (0,4,8,12)
  const int ah   = apos >> 3;            // A: which 32-elem half (0/1)
  const int aoff = (apos & 7) * 4;       // A: element offset in half-row (0/16)

  f32x4 acc[4][4];
  #pragma unroll
  for (int i = 0; i < 4; i++)
    #pragma unroll
    for (int j = 0; j < 4; j++)
      acc[i][j] = (f32x4){0.f, 0.f, 0.f, 0.f};

  const int* xr_a = x + (size_t)(row0      + arow) * NP + apos;  // rows 0..63
  const int* xr_b = x + (size_t)(row0 + 64 + arow) * NP + apos;  // rows 64..127

  // prologue: x int4 loads for kt=0 (16B, segment-coalesced)
  int4 xqa = *(const int4*)xr_a;
  int4 xqb = *(const int4*)xr_b;

  __syncthreads();   // table ready before first gather

  for (int kt = 0; kt < NK; ++kt) {
    // ---- B staging: async global->LDS, two 128x32 half-tiles ----
    const int k0 = kt * BK;
    #pragma unroll
    for (int h = 0; h < 2; ++h) {
      GLOAD_LDS16(Bt + (size_t)(col0      + srow) * KDIM + k0 + h * BKH + scol, Bs[h] + tid * 8);
      GLOAD_LDS16(Bt + (size_t)(col0 + 64 + srow) * KDIM + k0 + h * BKH + scol, Bs[h] + 2048 + tid * 8);
    }

    // ---- A materialization: 8 table gathers -> 4 x 16B LDS writes ----
    {
      uint16_t* da = As[ah] + arow * BKH + aoff;
      uint16_t* db = As[ah] + (64 + arow) * BKH + aoff;
      union { bf16x8 v; struct { bf16x4 lo, hi; } s; } u;
      u.s.lo = *(const bf16x4*)(web + ((unsigned)xqa.x * 4u));
      u.s.hi = *(const bf16x4*)(web + ((unsigned)xqa.y * 4u));
      *(bf16x8*)(da) = u.v;
      u.s.lo = *(const bf16x4*)(web + ((unsigned)xqa.z * 4u));
      u.s.hi = *(const bf16x4*)(web + ((unsigned)xqa.w * 4u));
      *(bf16x8*)(da + 8) = u.v;
      u.s.lo = *(const bf16x4*)(web + ((unsigned)xqb.x * 4u));
      u.s.hi = *(const bf16x4*)(web + ((unsigned)xqb.y * 4u));
      *(bf16x8*)(db) = u.v;
      u.s.lo = *(const bf16x4*)(web + ((unsigned)xqb.z * 4u));
      u.s.hi = *(const bf16x4*)(web + ((unsigned)xqb.w * 4u));
      *(bf16x8*)(db + 8) = u.v;
    }

    // ---- prefetch next K-step's x (drained by the barrier anyway) ----
    if (kt + 1 < NK) {
      xqa = *(const int4*)(xr_a + (kt + 1) * 16);
      xqb = *(const int4*)(xr_b + (kt + 1) * 16);
    }

    __syncthreads();

    #pragma unroll
    for (int h = 0; h < 2; ++h) {
      bf16x8 af[4], bfr[4];
      #pragma unroll
      for (int i = 0; i < 4; i++)
        af[i] = *(const bf16x8*)(As[h] + (wr * 64 + i * 16 + lm) * BKH + q * 8);
      #pragma unroll
      for (int j = 0; j < 4; j++)
        bfr[j] = *(const bf16x8*)(Bs[h] + (wc * 64 + j * 16 + lm) * BKH + q * 8);

      #pragma unroll
      for (int i = 0; i < 4; i++)
        #pragma unroll
        for (int j = 0; j < 4; j++)
          acc[i][j] = __builtin_amdgcn_mfma_f32_16x16x32_bf16(af[i], bfr[j], acc[i][j], 0, 0, 0);
    }

    __syncthreads();
  }

  // ---- epilogue: D[row = q*4 + r][col = lm] per 16x16 frag (m89/m91-verified) ----
  float bvals[4];
  #pragma unroll
  for (int j = 0; j < 4; j++)
    bvals[j] = bias[col0 + wc * 64 + j * 16 + lm];

  #pragma unroll
  for (int i = 0; i < 4; i++) {
    const int rbase = row0 + wr * 64 + i * 16 + q * 4;
    #pragma unroll
    for (int j = 0; j < 4; j++) {
      const int col = col0 + wc * 64 + j * 16 + lm;
      #pragma unroll
      for (int r = 0; r < 4; r++)
        C[(size_t)(rbase + r) * NDIM + col] = acc[i][j][r] + bvals[j];
    }
  }
}

// ---------------- fallback (workspace too small): fp32 naive ----------------
__global__ void naive_kernel(const int* __restrict__ x,
                             const float* __restrict__ We,
                             const float* __restrict__ be,
                             const float* __restrict__ Wd,
                             const float* __restrict__ bd,
                             float* __restrict__ out) {
  __shared__ float emb[KDIM];
  const int b = blockIdx.x;
  const int tid = threadIdx.x;
  {
    const int cls = x[(size_t)b * NP + tid];
    const float4 e  = *(const float4*)(We + (size_t)cls * 4);
    const float4 bb = *(const float4*)be;
    emb[tid * 4 + 0] = e.x + bb.x;
    emb[tid * 4 + 1] = e.y + bb.y;
    emb[tid * 4 + 2] = e.z + bb.z;
    emb[tid * 4 + 3] = e.w + bb.w;
  }
  __syncthreads();
  float acc0 = bd[tid], acc1 = bd[tid + 256], acc2 = bd[tid + 512], acc3 = bd[tid + 768];
  for (int k = 0; k < KDIM; ++k) {
    const float a = emb[k];
    const float* w = Wd + (size_t)k * NDIM + tid;
    acc0 += a * w[0];
    acc1 += a * w[256];
    acc2 += a * w[512];
    acc3 += a * w[768];
  }
  float* o = out + (size_t)b * NDIM + tid;
  o[0] = acc0; o[256] = acc1; o[512] = acc2; o[768] = acc3;
}

// ---------------- launch ----------------
extern "C" void kernel_launch(void* const* d_in, const int* in_sizes, int n_in,
                              void* d_out, int out_size, void* d_ws, size_t ws_size,
                              hipStream_t stream) {
  const int*   x  = (const int*)d_in[0];
  const float* We = (const float*)d_in[1];
  const float* be = (const float*)d_in[2];
  const float* Wd = (const float*)d_in[3];
  const float* bd = (const float*)d_in[4];
  float* out = (float*)d_out;

  const size_t needB = (size_t)NDIM * KDIM * sizeof(uint16_t);  // 2 MB

  if (ws_size >= needB) {
    uint16_t* Btw = (uint16_t*)d_ws;
    build_bt_kernel<<<dim3(NDIM / 32, KDIM / 32), dim3(32, 8), 0, stream>>>(Wd, Btw);
    fused_gemm_kernel<<<dim3(MB / BM, NDIM / BN), 256, 0, stream>>>(x, We, be, Btw, bd, out);
  } else {
    naive_kernel<<<MB, 256, 0, stream>>>(x, We, be, Wd, bd, out);
  }
}